// Round 3
// baseline (703.406 us; speedup 1.0000x reference)
//
#include <hip/hip_runtime.h>

#define NN 50000
#define EE 800000
#define LL 3
#define HH 4
#define CC 16
#define DD 64
#define GG 512
#define GRAPH_DIM 128

// ---------------------------------------------------------------------------
__global__ void zero_i32(int* p, int n) {
    int i = blockIdx.x * blockDim.x + threadIdx.x;
    if (i < n) p[i] = 0;
}
__global__ void zero_f32(float* p, int n) {
    int i = blockIdx.x * blockDim.x + threadIdx.x;
    if (i < n) p[i] = 0.f;
}

// ---------------------------------------------------------------------------
// CSR build: histogram of dst, exclusive scan, scatter (src, dst, attr)
// ---------------------------------------------------------------------------
__global__ void hist_kernel(const int* __restrict__ dst, int* __restrict__ counts) {
    int e = blockIdx.x * blockDim.x + threadIdx.x;
    if (e < EE) atomicAdd(&counts[dst[e]], 1);
}

__global__ __launch_bounds__(1024) void scan_kernel(const int* __restrict__ counts,
                                                    int* __restrict__ row_ptr,
                                                    int* __restrict__ writepos) {
    __shared__ int wsum[16];
    int t = threadIdx.x, lane = t & 63, wid = t >> 6;
    int base = 0;
    for (int start = 0; start < NN; start += 1024) {
        int idx = start + t;
        int val = (idx < NN) ? counts[idx] : 0;
        int x = val;
        #pragma unroll
        for (int o = 1; o < 64; o <<= 1) {
            int y = __shfl_up(x, o);
            if (lane >= o) x += y;
        }
        if (lane == 63) wsum[wid] = x;
        __syncthreads();
        if (wid == 0) {
            int s = (lane < 16) ? wsum[lane] : 0;
            #pragma unroll
            for (int o = 1; o < 16; o <<= 1) {
                int y = __shfl_up(s, o);
                if (lane >= o) s += y;
            }
            if (lane < 16) wsum[lane] = s;
        }
        __syncthreads();
        int excl = x - val + base + (wid > 0 ? wsum[wid - 1] : 0);
        if (idx < NN) { row_ptr[idx] = excl; writepos[idx] = excl; }
        int total = wsum[15];
        __syncthreads();
        base += total;
    }
    if (t == 0) row_ptr[NN] = base;
}

__global__ void scatter_kernel(const int* __restrict__ ei, const float* __restrict__ attr,
                               int* __restrict__ writepos,
                               int* __restrict__ src_s, int* __restrict__ dst_s,
                               float* __restrict__ attr_s) {
    int e = blockIdx.x * blockDim.x + threadIdx.x;
    if (e < EE) {
        int s = ei[e];
        int d = ei[EE + e];
        int p = atomicAdd(&writepos[d], 1);
        src_s[p] = s;
        dst_s[p] = d;
        attr_s[p] = attr[e];
    }
}

// ---------------------------------------------------------------------------
// fused node GEMM: q,k,v,skip = h @ {Wq,Wk,Wv,Ws} + biases
// ---------------------------------------------------------------------------
__global__ __launch_bounds__(256) void node_gemm(
    const float* __restrict__ hx,
    const float* __restrict__ Wq, const float* __restrict__ bq,
    const float* __restrict__ Wk, const float* __restrict__ bk,
    const float* __restrict__ Wv, const float* __restrict__ bv,
    const float* __restrict__ Ws, const float* __restrict__ bs,
    float* __restrict__ q, float* __restrict__ k,
    float* __restrict__ v, float* __restrict__ sk)
{
    __shared__ float xs[32 * 64];
    int t = threadIdx.x;
    int node0 = blockIdx.x * 32;

    const float4* src4 = (const float4*)(hx + (size_t)node0 * 64);
    float4* dst4 = (float4*)xs;
    #pragma unroll
    for (int r = 0; r < 2; ++r) {
        int i4 = t + r * 256;
        int node = node0 + (i4 >> 4);
        float4 val = make_float4(0.f, 0.f, 0.f, 0.f);
        if (node < NN) val = src4[i4];
        dst4[i4] = val;
    }
    __syncthreads();

    int mat = t >> 6, j = t & 63;
    const float* W = (mat == 0) ? Wq : (mat == 1) ? Wk : (mat == 2) ? Wv : Ws;
    const float* B = (mat == 0) ? bq : (mat == 1) ? bk : (mat == 2) ? bv : bs;
    float* O       = (mat == 0) ? q  : (mat == 1) ? k  : (mat == 2) ? v  : sk;

    float wcol[64];
    #pragma unroll
    for (int i = 0; i < 64; ++i) wcol[i] = W[i * 64 + j];
    float bj = B[j];

    for (int n = 0; n < 32; ++n) {
        int node = node0 + n;
        if (node >= NN) break;
        float acc = bj;
        const float4* xr = (const float4*)(xs + n * 64);
        #pragma unroll
        for (int i4 = 0; i4 < 16; ++i4) {
            float4 xv = xr[i4];
            acc = fmaf(xv.x, wcol[4 * i4 + 0], acc);
            acc = fmaf(xv.y, wcol[4 * i4 + 1], acc);
            acc = fmaf(xv.z, wcol[4 * i4 + 2], acc);
            acc = fmaf(xv.w, wcol[4 * i4 + 3], acc);
        }
        O[(size_t)node * 64 + j] = acc;
    }
}

// ---------------------------------------------------------------------------
// phase 1: edge-parallel scores. thread t -> (p = t>>2, h = t&3)
// ex[p*4+h] = exp( q[dst,h,:] . (k[src,h,:] + a*We[h,:]) / 4 )
// no cross-lane ops; 3.2M independent threads.
// ---------------------------------------------------------------------------
__global__ __launch_bounds__(256) void edge_score(
    const float* __restrict__ q, const float* __restrict__ k,
    const float* __restrict__ We,
    const int* __restrict__ src_s, const int* __restrict__ dst_s,
    const float* __restrict__ attr_s,
    float* __restrict__ ex_s)
{
    int t = blockIdx.x * 256 + threadIdx.x;
    if (t >= EE * HH) return;
    int p = t >> 2, h = t & 3;
    int s = src_s[p];
    int d = dst_s[p];
    float a = attr_s[p];
    const float4* kr = (const float4*)(k + (size_t)s * 64 + h * 16);
    const float4* qr = (const float4*)(q + (size_t)d * 64 + h * 16);
    const float4* wr = (const float4*)(We + h * 16);
    float dot = 0.f;
    #pragma unroll
    for (int i = 0; i < 4; ++i) {
        float4 kv = kr[i];
        float4 qv = qr[i];
        float4 wv = wr[i];
        dot = fmaf(qv.x, fmaf(a, wv.x, kv.x), dot);
        dot = fmaf(qv.y, fmaf(a, wv.y, kv.y), dot);
        dot = fmaf(qv.z, fmaf(a, wv.z, kv.z), dot);
        dot = fmaf(qv.w, fmaf(a, wv.w, kv.w), dot);
    }
    ex_s[t] = __expf(dot * 0.25f);
}

// ---------------------------------------------------------------------------
// phase 2: node aggregation. one wave per dst node, lane = channel.
// out = (sum ex*v[src] + we*sum ex*a) / (sum ex + 1e-16) + skip
// dependency chain per edge: index load -> v gather -> fma (no shuffles)
// ---------------------------------------------------------------------------
__global__ __launch_bounds__(256) void node_agg(
    const float* __restrict__ v, const float* __restrict__ sk,
    const float* __restrict__ We,
    const int* __restrict__ row_ptr, const int* __restrict__ src_s,
    const float* __restrict__ attr_s, const float* __restrict__ ex_s,
    float* __restrict__ out, int do_relu, int do_pool,
    const int* __restrict__ batch,
    float* __restrict__ gsum, float* __restrict__ gcnt)
{
    int node = blockIdx.x * 4 + (threadIdx.x >> 6);
    int lane = threadIdx.x & 63;
    if (node >= NN) return;

    int h = lane >> 4;
    size_t nb = (size_t)node * 64;
    float skv = sk[nb + lane];
    float we = We[lane];

    int p0 = row_ptr[node];
    int p1 = row_ptr[node + 1];

    float acc = 0.f, den = 0.f, saw = 0.f;
    int p = p0;
    for (; p + 4 <= p1; p += 4) {
        int s0 = src_s[p + 0], s1 = src_s[p + 1];
        int s2 = src_s[p + 2], s3 = src_s[p + 3];
        float a0 = attr_s[p + 0], a1 = attr_s[p + 1];
        float a2 = attr_s[p + 2], a3 = attr_s[p + 3];
        float e0 = ex_s[(p + 0) * 4 + h], e1 = ex_s[(p + 1) * 4 + h];
        float e2 = ex_s[(p + 2) * 4 + h], e3 = ex_s[(p + 3) * 4 + h];
        float v0 = v[(size_t)s0 * 64 + lane];
        float v1 = v[(size_t)s1 * 64 + lane];
        float v2 = v[(size_t)s2 * 64 + lane];
        float v3 = v[(size_t)s3 * 64 + lane];
        acc = fmaf(e0, v0, acc); den += e0; saw = fmaf(e0, a0, saw);
        acc = fmaf(e1, v1, acc); den += e1; saw = fmaf(e1, a1, saw);
        acc = fmaf(e2, v2, acc); den += e2; saw = fmaf(e2, a2, saw);
        acc = fmaf(e3, v3, acc); den += e3; saw = fmaf(e3, a3, saw);
    }
    for (; p < p1; ++p) {
        int s = src_s[p];
        float a = attr_s[p];
        float e = ex_s[p * 4 + h];
        float vv = v[(size_t)s * 64 + lane];
        acc = fmaf(e, vv, acc); den += e; saw = fmaf(e, a, saw);
    }

    float o = (acc + saw * we) / (den + 1e-16f) + skv;
    if (do_relu) o = fmaxf(o, 0.f);
    out[nb + lane] = o;

    if (do_pool) {
        int b = batch[node];
        atomicAdd(&gsum[(size_t)b * 64 + lane], o);
        if (lane == 0) atomicAdd(&gcnt[b], 1.f);
    }
}

// ---------------------------------------------------------------------------
// mean-pool finalize + 3-layer MLP head; one block (128 thr) per graph
// ---------------------------------------------------------------------------
__global__ __launch_bounds__(128) void pool_mlp(
    const float* __restrict__ gsum, const float* __restrict__ gcnt,
    const float* __restrict__ W1, const float* __restrict__ b1,
    const float* __restrict__ W2, const float* __restrict__ b2,
    const float* __restrict__ W3, const float* __restrict__ b3,
    float* __restrict__ out)
{
    __shared__ float g[64];
    __shared__ float h1s[64];
    __shared__ float h2s[16];
    int b = blockIdx.x, t = threadIdx.x;

    if (t < 64) {
        float c = gcnt[b];
        g[t] = gsum[(size_t)b * 64 + t] / fmaxf(c, 1.f);
    }
    __syncthreads();
    if (t < 64) {
        float a = b1[t];
        #pragma unroll
        for (int i = 0; i < 64; ++i) a = fmaf(g[i], W1[i * 64 + t], a);
        h1s[t] = fmaxf(a, 0.f);
    }
    __syncthreads();
    if (t < 16) {
        float a = b2[t];
        #pragma unroll
        for (int i = 0; i < 64; ++i) a = fmaf(h1s[i], W2[i * 16 + t], a);
        h2s[t] = fmaxf(a, 0.f);
    }
    __syncthreads();
    float a = b3[t];
    #pragma unroll
    for (int i = 0; i < 16; ++i) a = fmaf(h2s[i], W3[i * 128 + t], a);
    out[(size_t)b * 128 + t] = a;
}

// ---------------------------------------------------------------------------
extern "C" void kernel_launch(void* const* d_in, const int* in_sizes, int n_in,
                              void* d_out, int out_size, void* d_ws, size_t ws_size,
                              hipStream_t stream) {
    const float* x         = (const float*)d_in[0];
    const float* edge_attr = (const float*)d_in[1];
    const int*   edge_index= (const int*)d_in[2];
    const int*   batch     = (const int*)d_in[3];
    const float* Wq   = (const float*)d_in[4];
    const float* bq   = (const float*)d_in[5];
    const float* Wk   = (const float*)d_in[6];
    const float* bk   = (const float*)d_in[7];
    const float* Wv   = (const float*)d_in[8];
    const float* bv   = (const float*)d_in[9];
    const float* We   = (const float*)d_in[10];
    const float* Wsk  = (const float*)d_in[11];
    const float* bsk  = (const float*)d_in[12];
    const float* W1   = (const float*)d_in[13];
    const float* b1   = (const float*)d_in[14];
    const float* W2   = (const float*)d_in[15];
    const float* b2   = (const float*)d_in[16];
    const float* W3   = (const float*)d_in[17];
    const float* b3   = (const float*)d_in[18];

    float* out        = (float*)d_out;
    float* node_emb   = out;                         // N*64
    float* graph_feat = out + (size_t)NN * 64;       // G*128

    float* wsf    = (float*)d_ws;
    float* q      = wsf;
    float* k      = q    + (size_t)NN * 64;
    float* v      = k    + (size_t)NN * 64;
    float* skp    = v    + (size_t)NN * 64;
    float* h      = skp  + (size_t)NN * 64;
    float* attr_s = h    + (size_t)NN * 64;
    float* ex_s   = attr_s + EE;
    int*   src_s  = (int*)(ex_s + (size_t)EE * HH);
    int*   dst_s  = src_s + EE;
    int*   row_ptr= dst_s + EE;
    int*   wpos   = row_ptr + (NN + 1);
    float* gsum   = (float*)(wpos + NN);
    float* gcnt   = gsum + (size_t)GG * 64;

    // ---- CSR build (dst-sorted edges); reused by all 3 layers ----
    zero_i32<<<(NN + 255) / 256, 256, 0, stream>>>(wpos, NN);
    zero_f32<<<(GG * 64 + GG + 255) / 256, 256, 0, stream>>>(gsum, GG * 64 + GG);
    hist_kernel<<<(EE + 255) / 256, 256, 0, stream>>>(edge_index + EE, wpos);
    scan_kernel<<<1, 1024, 0, stream>>>(wpos, row_ptr, wpos);
    scatter_kernel<<<(EE + 255) / 256, 256, 0, stream>>>(edge_index, edge_attr,
                                                         wpos, src_s, dst_s, attr_s);

    int gemm_grid  = (NN + 31) / 32;
    int agg_grid   = (NN + 3) / 4;
    int score_grid = (EE * HH + 255) / 256;

    const float* layer_in = x;
    for (int l = 0; l < LL; ++l) {
        const float* Wq_l = Wq + (size_t)l * 64 * 64;
        const float* Wk_l = Wk + (size_t)l * 64 * 64;
        const float* Wv_l = Wv + (size_t)l * 64 * 64;
        const float* Ws_l = Wsk + (size_t)l * 64 * 64;
        const float* bq_l = bq + (size_t)l * 64;
        const float* bk_l = bk + (size_t)l * 64;
        const float* bv_l = bv + (size_t)l * 64;
        const float* bs_l = bsk + (size_t)l * 64;
        const float* We_l = We + (size_t)l * 64;

        node_gemm<<<gemm_grid, 256, 0, stream>>>(layer_in,
            Wq_l, bq_l, Wk_l, bk_l, Wv_l, bv_l, Ws_l, bs_l,
            q, k, v, skp);

        edge_score<<<score_grid, 256, 0, stream>>>(q, k, We_l,
            src_s, dst_s, attr_s, ex_s);

        int last = (l == LL - 1);
        float* dst_h = last ? node_emb : h;
        node_agg<<<agg_grid, 256, 0, stream>>>(v, skp, We_l,
            row_ptr, src_s, attr_s, ex_s,
            dst_h, /*relu=*/!last, /*pool=*/last,
            batch, gsum, gcnt);

        layer_in = h;
    }

    pool_mlp<<<GG, 128, 0, stream>>>(gsum, gcnt, W1, b1, W2, b2, W3, b3, graph_feat);
}